// Round 7
// baseline (229.939 us; speedup 1.0000x reference)
//
#include <hip/hip_runtime.h>
#include <hip/hip_bf16.h>

#define N_NODES 20000
#define N_EDGES 320000
#define F_IN    128
#define F_HID   32
#define NHEAD   8
#define FDIM    256   // NHEAD * D for both layers
#define CAP     96    // max in-degree capacity; P(Poisson(16) > 96) ~ 1e-44

typedef __hip_bfloat16 bf16;

// ---------------- bucket build ----------------
__global__ void zero_kernel(int* __restrict__ p, int n){
  int i = blockIdx.x*256 + threadIdx.x;
  if (i < n) p[i] = 0;
}

__global__ void fill_bucket_kernel(const int* __restrict__ src, const int* __restrict__ dst,
                                   int* __restrict__ cnt, int* __restrict__ bucket, int e){
  int i = blockIdx.x*256 + threadIdx.x;
  if (i < e){
    int d = dst[i];
    int p = atomicAdd(&cnt[d], 1);
    if (p < CAP) bucket[(size_t)d*CAP + p] = src[i];
  }
}

// ---------------- feat = x @ W ; el/er = head-dot with al/ar ----------------
// block = 256 threads (thread = output column), 16 nodes per block.
// NO LDS: x is read with block-uniform addresses straight from global so the
// compiler emits scalar (s_load) reads through the K$ — round-6 lesson: LDS
// wave-uniform broadcasts burn 1024 B of LDS BW per 16 useful bytes and were
// the 47 us bottleneck. W streams per-lane with a register double-buffer;
// kk loop kept ROLLED (#pragma unroll 1) — full unroll spills (round-4: 29x).
template<int K, int NODES>
__global__ __launch_bounds__(256) void gemm_aux_kernel(
    const float* __restrict__ x, const float* __restrict__ W,
    const float* __restrict__ al, const float* __restrict__ ar,
    bf16* __restrict__ feat, float* __restrict__ el, float* __restrict__ er)
{
  const int tid = threadIdx.x;
  const int n0  = blockIdx.x * NODES;

  float wr[8];
  #pragma unroll
  for (int j = 0; j < 8; j++) wr[j] = W[j*FDIM + tid];

  float acc[NODES];
  #pragma unroll
  for (int nn = 0; nn < NODES; nn++) acc[nn] = 0.f;

  #pragma unroll 1
  for (int kk = 0; kk < K; kk += 8){
    float wn[8];
    const bool more = (kk + 8 < K);
    if (more){
      #pragma unroll
      for (int j = 0; j < 8; j++) wn[j] = W[(kk+8+j)*FDIM + tid];  // prefetch next chunk
    }
    #pragma unroll
    for (int nn = 0; nn < NODES; nn++){
      const float* xp = x + (size_t)(n0 + nn)*K + kk;   // block-uniform -> s_load
      acc[nn] = fmaf(xp[0], wr[0], acc[nn]);
      acc[nn] = fmaf(xp[1], wr[1], acc[nn]);
      acc[nn] = fmaf(xp[2], wr[2], acc[nn]);
      acc[nn] = fmaf(xp[3], wr[3], acc[nn]);
      acc[nn] = fmaf(xp[4], wr[4], acc[nn]);
      acc[nn] = fmaf(xp[5], wr[5], acc[nn]);
      acc[nn] = fmaf(xp[6], wr[6], acc[nn]);
      acc[nn] = fmaf(xp[7], wr[7], acc[nn]);
    }
    if (more){
      #pragma unroll
      for (int j = 0; j < 8; j++) wr[j] = wn[j];
    }
  }

  const float alv = al[tid];
  const float arv = ar[tid];
  #pragma unroll
  for (int nn = 0; nn < NODES; nn++){
    const int nidx = n0 + nn;
    feat[(size_t)nidx*FDIM + tid] = __float2bfloat16(acc[nn]);
    float e_l = acc[nn] * alv;
    float e_r = acc[nn] * arv;
    #pragma unroll
    for (int off = 16; off >= 1; off >>= 1){
      e_l += __shfl_xor(e_l, off);   // stays within the 32-lane head group
      e_r += __shfl_xor(e_r, off);
    }
    if ((tid & 31) == 0){
      el[nidx*NHEAD + (tid >> 5)] = e_l;
      er[nidx*NHEAD + (tid >> 5)] = e_r;
    }
  }
}

// ---------------- per-dst-node edge softmax + aggregate ----------------
// WAVE-PER-NODE: 4 waves/block, each wave owns one node; all cross-lane
// traffic stays inside the wave (lockstep) -> ZERO __syncthreads. Per-wave
// LDS slices. Phase B: half-wave per edge, dwordx4 gathers (2 edges/wave-inst).
template<int RELU_MEAN>
__global__ __launch_bounds__(256) void edge_agg_kernel(
    const bf16* __restrict__ feat, const float* __restrict__ el,
    const float* __restrict__ er, const int* __restrict__ cnt,
    const int* __restrict__ bucket, const float* __restrict__ bias,
    float* __restrict__ outp)
{
  const int tid  = threadIdx.x;
  const int wv   = tid >> 6;
  const int lane = tid & 63;
  const int n    = blockIdx.x*4 + wv;

  __shared__ float t_all[4][CAP*9];   // stride 9: conflict-free
  __shared__ int   s_all[4][CAP];
  __shared__ float sum_all[4][NHEAD];
  __shared__ float v_all[4][256];
  float* t_w = t_all[wv];
  int*   s_w = s_all[wv];

  int C = cnt[n];
  if (C > CAP) C = CAP;

  // er row (uniform address, scalar/L1 broadcast)
  const float4* er4 = (const float4*)(er + (size_t)n*NHEAD);
  float4 era = er4[0], erb = er4[1];
  const float erv[8] = {era.x, era.y, era.z, era.w, erb.x, erb.y, erb.z, erb.w};

  // ---- Phase A: logits for this node's edges ----
  for (int e = lane; e < C; e += 64){
    const int sidx = bucket[(size_t)n*CAP + e];
    s_w[e] = sidx;
    const float4* e4 = (const float4*)(el + (size_t)sidx*NHEAD);
    float4 a = e4[0], bq = e4[1];
    float ev[8] = {a.x, a.y, a.z, a.w, bq.x, bq.y, bq.z, bq.w};
    #pragma unroll
    for (int hh = 0; hh < 8; hh++){
      float v = ev[hh] + erv[hh];
      t_w[e*9 + hh] = (v > 0.f) ? v : 0.2f*v;   // leaky_relu(0.2)
    }
  }
  // per-head max + exp + denominator: 8 lanes per head (h = lane>>3, d = lane&7)
  {
    const int h = lane >> 3, d = lane & 7;
    float lm = -INFINITY;
    for (int e = d; e < C; e += 8) lm = fmaxf(lm, t_w[e*9 + h]);
    #pragma unroll
    for (int off = 4; off >= 1; off >>= 1) lm = fmaxf(lm, __shfl_xor(lm, off));
    float ls = 0.f;
    for (int e = d; e < C; e += 8){
      float ex = __expf(t_w[e*9 + h] - lm);
      t_w[e*9 + h] = ex;       // weight stored in place (owner-writes)
      ls += ex;
    }
    #pragma unroll
    for (int off = 4; off >= 1; off >>= 1) ls += __shfl_xor(ls, off);
    if (d == 0) sum_all[wv][h] = ls;
  }

  // ---- Phase B: weighted aggregation, half-wave per edge, 8 cols/lane ----
  const int sub = lane >> 5;        // which edge of the pair
  const int l   = lane & 31;        // 32 lanes cover 256 cols, 8 each
  const int hB  = l >> 2;           // head owning cols 8l..8l+7
  float acc[8] = {0,0,0,0,0,0,0,0};
  for (int e = sub; e < C; e += 2){
    const int sidx = s_w[e];
    const float4 fv = *(const float4*)(feat + (size_t)sidx*FDIM + (l << 3));
    const float w = t_w[e*9 + hB];
    const unsigned* u = (const unsigned*)&fv;
    #pragma unroll
    for (int j = 0; j < 4; j++){
      float flo = __uint_as_float(u[j] << 16);           // col 8l+2j
      float fhi = __uint_as_float(u[j] & 0xFFFF0000u);   // col 8l+2j+1
      acc[2*j]   = fmaf(w, flo, acc[2*j]);
      acc[2*j+1] = fmaf(w, fhi, acc[2*j+1]);
    }
  }
  #pragma unroll
  for (int j = 0; j < 8; j++) acc[j] += __shfl_xor(acc[j], 32);  // fold edge pair

  // ---- epilogue (wave-local): divide, bias, relu, head-mean ----
  if (lane < 32){
    const float s = sum_all[wv][l >> 2];
    const float4* b4 = (const float4*)(bias + (l << 3));
    float4 ba = b4[0], bb = b4[1];
    float bv[8] = {ba.x, ba.y, ba.z, ba.w, bb.x, bb.y, bb.z, bb.w};
    float v[8];
    #pragma unroll
    for (int j = 0; j < 8; j++){
      float val = (C > 0) ? (acc[j] / s) : 0.f;
      val += bv[j];
      if (RELU_MEAN) val = fmaxf(val, 0.f);
      v[j] = val;
    }
    float4* v4 = (float4*)&v_all[wv][l << 3];
    v4[0] = make_float4(v[0], v[1], v[2], v[3]);
    v4[1] = make_float4(v[4], v[5], v[6], v[7]);
  }
  if (lane < 32){
    float sum = 0.f;
    #pragma unroll
    for (int hh = 0; hh < 8; hh++) sum += v_all[wv][hh*32 + lane];
    sum *= 0.125f;   // mean over heads
    outp[(size_t)n*32 + lane] = sum;
  }
}

extern "C" void kernel_launch(void* const* d_in, const int* in_sizes, int n_in,
                              void* d_out, int out_size, void* d_ws, size_t ws_size,
                              hipStream_t stream)
{
  const float* x   = (const float*)d_in[0];
  const int*   src = (const int*)  d_in[1];
  const int*   dst = (const int*)  d_in[2];
  const float* W1  = (const float*)d_in[3];
  const float* al1 = (const float*)d_in[4];
  const float* ar1 = (const float*)d_in[5];
  const float* b1  = (const float*)d_in[6];
  const float* W2  = (const float*)d_in[7];
  const float* al2 = (const float*)d_in[8];
  const float* ar2 = (const float*)d_in[9];
  const float* b2  = (const float*)d_in[10];
  (void)in_sizes; (void)n_in; (void)out_size; (void)ws_size;

  size_t o = 0;
  char* base = (char*)d_ws;
  auto take = [&](size_t bytes) -> char* {
    char* p = base + o;
    o += (bytes + 255) & ~(size_t)255;
    return p;
  };
  bf16*  feat   = (bf16*) take((size_t)N_NODES*FDIM*2);
  float* el     = (float*)take((size_t)N_NODES*NHEAD*4);
  float* er     = (float*)take((size_t)N_NODES*NHEAD*4);
  float* hbuf   = (float*)take((size_t)N_NODES*F_HID*4);
  int*   cnt    = (int*)  take((size_t)N_NODES*4);
  int*   bucket = (int*)  take((size_t)N_NODES*CAP*4);

  // bucket build (shared by both layers)
  zero_kernel<<<(N_NODES+255)/256, 256, 0, stream>>>(cnt, N_NODES);
  fill_bucket_kernel<<<(N_EDGES+255)/256, 256, 0, stream>>>(src, dst, cnt, bucket, N_EDGES);

  // layer 1
  gemm_aux_kernel<F_IN, 16><<<N_NODES/16, 256, 0, stream>>>(x, W1, al1, ar1, feat, el, er);
  edge_agg_kernel<1><<<N_NODES/4, 256, 0, stream>>>(feat, el, er, cnt, bucket, b1, hbuf);

  // layer 2
  gemm_aux_kernel<F_HID, 16><<<N_NODES/16, 256, 0, stream>>>(hbuf, W2, al2, ar2, feat, el, er);
  edge_agg_kernel<0><<<N_NODES/4, 256, 0, stream>>>(feat, el, er, cnt, bucket, b2, (float*)d_out);
}

// Round 8
// 209.749 us; speedup vs baseline: 1.0963x; 1.0963x over previous
//
#include <hip/hip_runtime.h>
#include <hip/hip_bf16.h>

#define N_NODES 20000
#define N_EDGES 320000
#define F_IN    128
#define F_HID   32
#define NHEAD   8
#define FDIM    256   // NHEAD * D for both layers
#define CAP     96    // max in-degree capacity; P(Poisson(16) > 96) ~ 1e-44

typedef __hip_bfloat16 bf16;
typedef __attribute__((ext_vector_type(8))) short short8;
typedef __attribute__((ext_vector_type(4))) float f32x4;

// bf16 round-to-nearest-even on raw bits (avoids type plumbing)
__device__ __forceinline__ unsigned short f2bf_rne(float f){
  unsigned u = __float_as_uint(f);
  unsigned r = u + 0x7FFFu + ((u >> 16) & 1u);
  return (unsigned short)(r >> 16);
}
__device__ __forceinline__ float bf2f(unsigned short s){
  return __uint_as_float((unsigned)s << 16);
}

// ---------------- bucket build ----------------
__global__ void zero_kernel(int* __restrict__ p, int n){
  int i = blockIdx.x*256 + threadIdx.x;
  if (i < n) p[i] = 0;
}

__global__ void fill_bucket_kernel(const int* __restrict__ src, const int* __restrict__ dst,
                                   int* __restrict__ cnt, int* __restrict__ bucket, int e){
  int i = blockIdx.x*256 + threadIdx.x;
  if (i < e){
    int d = dst[i];
    int p = atomicAdd(&cnt[d], 1);
    if (p < CAP) bucket[(size_t)d*CAP + p] = src[i];
  }
}

// ---------------- fp32 -> bf16 hi/lo split (elementwise, float4) ----------------
__global__ void split_kernel(const float* __restrict__ in,
                             unsigned short* __restrict__ hi,
                             unsigned short* __restrict__ lo, int n4){
  int i = blockIdx.x*256 + threadIdx.x;
  if (i < n4){
    float4 v = ((const float4*)in)[i];
    ushort4 h, l;
    h.x = f2bf_rne(v.x); l.x = f2bf_rne(v.x - bf2f(h.x));
    h.y = f2bf_rne(v.y); l.y = f2bf_rne(v.y - bf2f(h.y));
    h.z = f2bf_rne(v.z); l.z = f2bf_rne(v.z - bf2f(h.z));
    h.w = f2bf_rne(v.w); l.w = f2bf_rne(v.w - bf2f(h.w));
    ((ushort4*)hi)[i] = h;
    ((ushort4*)lo)[i] = l;
  }
}

// ---------------- W[K][256] -> Wt[256][K] hi/lo split ----------------
template<int K>
__global__ void splitT_kernel(const float* __restrict__ W,
                              unsigned short* __restrict__ hi,
                              unsigned short* __restrict__ lo){
  int i = blockIdx.x*256 + threadIdx.x;   // over 256*K, out-coalesced
  int n = i / K, k = i - n*K;
  float v = W[(size_t)k*FDIM + n];
  unsigned short hs = f2bf_rne(v);
  hi[i] = hs;
  lo[i] = f2bf_rne(v - bf2f(hs));
}

// ---------------- MFMA GEMM: feat = X @ W (bf16x3 split) + el/er ----------------
// Block = 256 thr = 4 waves; block computes 16 rows x 256 cols.
// Wave wv covers cols [wv*64, wv*64+64) as 4 16x16 tiles; A-frags (per m89
// layout A[m=lane&15][k=quad*8+j]) loaded once, reused over tiles.
// bf16x3: D += Ah*Bh + Ah*Bl + Al*Bh  (lo*lo dropped; ~2^-18 rel err).
// el/er computed from fp32 C fragments (no extra rounding), reduced via
// shfl within the 16-lane col group, then tiny LDS transpose.
template<int K>
__global__ __launch_bounds__(256) void gemm_mfma_kernel(
    const unsigned short* __restrict__ Xhi, const unsigned short* __restrict__ Xlo,
    const unsigned short* __restrict__ Wthi, const unsigned short* __restrict__ Wtlo,
    const float* __restrict__ al, const float* __restrict__ ar,
    unsigned short* __restrict__ feat, float* __restrict__ el, float* __restrict__ er)
{
  const int tid  = threadIdx.x;
  const int wv   = tid >> 6;
  const int lane = tid & 63;
  const int quad = lane >> 4;
  const int l16  = lane & 15;
  const int m0   = blockIdx.x * 16;
  constexpr int NC = K / 32;

  short8 Ah[NC], Al_[NC];
  const size_t arow = (size_t)(m0 + l16) * K;
  #pragma unroll
  for (int c = 0; c < NC; c++){
    Ah[c]  = *(const short8*)(Xhi + arow + c*32 + quad*8);
    Al_[c] = *(const short8*)(Xlo + arow + c*32 + quad*8);
  }

  float elp[8], erp[8];   // [r*2 + hloc], r=reg 0..3, hloc = tile>>1
  #pragma unroll
  for (int j = 0; j < 8; j++){ elp[j] = 0.f; erp[j] = 0.f; }

  #pragma unroll
  for (int t = 0; t < 4; t++){
    const int nc = wv*64 + t*16;
    const size_t brow = (size_t)(nc + l16) * K;
    f32x4 acc = {0.f, 0.f, 0.f, 0.f};
    #pragma unroll
    for (int c = 0; c < NC; c++){
      short8 Bh = *(const short8*)(Wthi + brow + c*32 + quad*8);
      short8 Bl = *(const short8*)(Wtlo + brow + c*32 + quad*8);
      acc = __builtin_amdgcn_mfma_f32_16x16x32_bf16(Ah[c],  Bh, acc, 0, 0, 0);
      acc = __builtin_amdgcn_mfma_f32_16x16x32_bf16(Ah[c],  Bl, acc, 0, 0, 0);
      acc = __builtin_amdgcn_mfma_f32_16x16x32_bf16(Al_[c], Bh, acc, 0, 0, 0);
    }
    const float alv = al[nc + l16];
    const float arv = ar[nc + l16];
    const int hl = t >> 1;
    #pragma unroll
    for (int r = 0; r < 4; r++){
      float v = acc[r];                       // C: row = quad*4+r, col = nc+l16
      feat[(size_t)(m0 + quad*4 + r)*FDIM + nc + l16] = f2bf_rne(v);
      elp[r*2 + hl] = fmaf(v, alv, elp[r*2 + hl]);
      erp[r*2 + hl] = fmaf(v, arv, erp[r*2 + hl]);
    }
  }

  // reduce over the 16 col-lanes (stays within quad: offsets 1..8)
  #pragma unroll
  for (int off = 1; off <= 8; off <<= 1){
    #pragma unroll
    for (int j = 0; j < 8; j++){
      elp[j] += __shfl_xor(elp[j], off);
      erp[j] += __shfl_xor(erp[j], off);
    }
  }
  __shared__ float el_lds[16][8], er_lds[16][8];
  if (l16 == 0){
    #pragma unroll
    for (int r = 0; r < 4; r++){
      #pragma unroll
      for (int hl = 0; hl < 2; hl++){
        el_lds[quad*4 + r][wv*2 + hl] = elp[r*2 + hl];
        er_lds[quad*4 + r][wv*2 + hl] = erp[r*2 + hl];
      }
    }
  }
  __syncthreads();
  if (tid < 128){
    int row = tid >> 3, h = tid & 7;
    el[(size_t)(m0 + row)*NHEAD + h] = el_lds[row][h];
    er[(size_t)(m0 + row)*NHEAD + h] = er_lds[row][h];
  }
}

// ---------------- per-dst-node edge softmax + aggregate ----------------
// WAVE-PER-NODE: 4 waves/block, each wave owns one node; zero __syncthreads.
template<int RELU_MEAN>
__global__ __launch_bounds__(256) void edge_agg_kernel(
    const bf16* __restrict__ feat, const float* __restrict__ el,
    const float* __restrict__ er, const int* __restrict__ cnt,
    const int* __restrict__ bucket, const float* __restrict__ bias,
    float* __restrict__ outp)
{
  const int tid  = threadIdx.x;
  const int wv   = tid >> 6;
  const int lane = tid & 63;
  const int n    = blockIdx.x*4 + wv;

  __shared__ float t_all[4][CAP*9];   // stride 9: conflict-free
  __shared__ int   s_all[4][CAP];
  __shared__ float sum_all[4][NHEAD];
  __shared__ float v_all[4][256];
  float* t_w = t_all[wv];
  int*   s_w = s_all[wv];

  int C = cnt[n];
  if (C > CAP) C = CAP;

  const float4* er4 = (const float4*)(er + (size_t)n*NHEAD);
  float4 era = er4[0], erb = er4[1];
  const float erv[8] = {era.x, era.y, era.z, era.w, erb.x, erb.y, erb.z, erb.w};

  // ---- Phase A: logits ----
  for (int e = lane; e < C; e += 64){
    const int sidx = bucket[(size_t)n*CAP + e];
    s_w[e] = sidx;
    const float4* e4 = (const float4*)(el + (size_t)sidx*NHEAD);
    float4 a = e4[0], bq = e4[1];
    float ev[8] = {a.x, a.y, a.z, a.w, bq.x, bq.y, bq.z, bq.w};
    #pragma unroll
    for (int hh = 0; hh < 8; hh++){
      float v = ev[hh] + erv[hh];
      t_w[e*9 + hh] = (v > 0.f) ? v : 0.2f*v;   // leaky_relu(0.2)
    }
  }
  // per-head max + exp + denominator: 8 lanes per head
  {
    const int h = lane >> 3, d = lane & 7;
    float lm = -INFINITY;
    for (int e = d; e < C; e += 8) lm = fmaxf(lm, t_w[e*9 + h]);
    #pragma unroll
    for (int off = 4; off >= 1; off >>= 1) lm = fmaxf(lm, __shfl_xor(lm, off));
    float ls = 0.f;
    for (int e = d; e < C; e += 8){
      float ex = __expf(t_w[e*9 + h] - lm);
      t_w[e*9 + h] = ex;
      ls += ex;
    }
    #pragma unroll
    for (int off = 4; off >= 1; off >>= 1) ls += __shfl_xor(ls, off);
    if (d == 0) sum_all[wv][h] = ls;
  }

  // ---- Phase B: weighted aggregation, half-wave per edge, dwordx4 bf16 ----
  const int sub = lane >> 5;
  const int l   = lane & 31;
  const int hB  = l >> 2;
  float acc[8] = {0,0,0,0,0,0,0,0};
  for (int e = sub; e < C; e += 2){
    const int sidx = s_w[e];
    const float4 fv = *(const float4*)(feat + (size_t)sidx*FDIM + (l << 3));
    const float w = t_w[e*9 + hB];
    const unsigned* u = (const unsigned*)&fv;
    #pragma unroll
    for (int j = 0; j < 4; j++){
      float flo = __uint_as_float(u[j] << 16);
      float fhi = __uint_as_float(u[j] & 0xFFFF0000u);
      acc[2*j]   = fmaf(w, flo, acc[2*j]);
      acc[2*j+1] = fmaf(w, fhi, acc[2*j+1]);
    }
  }
  #pragma unroll
  for (int j = 0; j < 8; j++) acc[j] += __shfl_xor(acc[j], 32);

  // ---- epilogue (wave-local) ----
  if (lane < 32){
    const float s = sum_all[wv][l >> 2];
    const float4* b4 = (const float4*)(bias + (l << 3));
    float4 ba = b4[0], bb = b4[1];
    float bv[8] = {ba.x, ba.y, ba.z, ba.w, bb.x, bb.y, bb.z, bb.w};
    float v[8];
    #pragma unroll
    for (int j = 0; j < 8; j++){
      float val = (C > 0) ? (acc[j] / s) : 0.f;
      val += bv[j];
      if (RELU_MEAN) val = fmaxf(val, 0.f);
      v[j] = val;
    }
    float4* v4 = (float4*)&v_all[wv][l << 3];
    v4[0] = make_float4(v[0], v[1], v[2], v[3]);
    v4[1] = make_float4(v[4], v[5], v[6], v[7]);
  }
  if (lane < 32){
    float sum = 0.f;
    #pragma unroll
    for (int hh = 0; hh < 8; hh++) sum += v_all[wv][hh*32 + lane];
    sum *= 0.125f;
    outp[(size_t)n*32 + lane] = sum;
  }
}

extern "C" void kernel_launch(void* const* d_in, const int* in_sizes, int n_in,
                              void* d_out, int out_size, void* d_ws, size_t ws_size,
                              hipStream_t stream)
{
  const float* x   = (const float*)d_in[0];
  const int*   src = (const int*)  d_in[1];
  const int*   dst = (const int*)  d_in[2];
  const float* W1  = (const float*)d_in[3];
  const float* al1 = (const float*)d_in[4];
  const float* ar1 = (const float*)d_in[5];
  const float* b1  = (const float*)d_in[6];
  const float* W2  = (const float*)d_in[7];
  const float* al2 = (const float*)d_in[8];
  const float* ar2 = (const float*)d_in[9];
  const float* b2  = (const float*)d_in[10];
  (void)in_sizes; (void)n_in; (void)out_size; (void)ws_size;

  size_t o = 0;
  char* base = (char*)d_ws;
  auto take = [&](size_t bytes) -> char* {
    char* p = base + o;
    o += (bytes + 255) & ~(size_t)255;
    return p;
  };
  unsigned short* feat  = (unsigned short*)take((size_t)N_NODES*FDIM*2);
  float* el     = (float*)take((size_t)N_NODES*NHEAD*4);
  float* er     = (float*)take((size_t)N_NODES*NHEAD*4);
  float* hbuf   = (float*)take((size_t)N_NODES*F_HID*4);
  int*   cnt    = (int*)  take((size_t)N_NODES*4);
  int*   bucket = (int*)  take((size_t)N_NODES*CAP*4);
  unsigned short* Xhi  = (unsigned short*)take((size_t)N_NODES*F_IN*2);
  unsigned short* Xlo  = (unsigned short*)take((size_t)N_NODES*F_IN*2);
  unsigned short* Hhi  = (unsigned short*)take((size_t)N_NODES*F_HID*2);
  unsigned short* Hlo  = (unsigned short*)take((size_t)N_NODES*F_HID*2);
  unsigned short* W1th = (unsigned short*)take((size_t)FDIM*F_IN*2);
  unsigned short* W1tl = (unsigned short*)take((size_t)FDIM*F_IN*2);
  unsigned short* W2th = (unsigned short*)take((size_t)FDIM*F_HID*2);
  unsigned short* W2tl = (unsigned short*)take((size_t)FDIM*F_HID*2);

  // bucket build (shared by both layers) + input conversions
  zero_kernel<<<(N_NODES+255)/256, 256, 0, stream>>>(cnt, N_NODES);
  fill_bucket_kernel<<<(N_EDGES+255)/256, 256, 0, stream>>>(src, dst, cnt, bucket, N_EDGES);
  split_kernel<<<(N_NODES*F_IN/4+255)/256, 256, 0, stream>>>(x, Xhi, Xlo, N_NODES*F_IN/4);
  splitT_kernel<F_IN ><<<(FDIM*F_IN )/256, 256, 0, stream>>>(W1, W1th, W1tl);
  splitT_kernel<F_HID><<<(FDIM*F_HID)/256, 256, 0, stream>>>(W2, W2th, W2tl);

  // layer 1
  gemm_mfma_kernel<F_IN><<<N_NODES/16, 256, 0, stream>>>(
      Xhi, Xlo, W1th, W1tl, al1, ar1, feat, el, er);
  edge_agg_kernel<1><<<N_NODES/4, 256, 0, stream>>>(
      (const bf16*)feat, el, er, cnt, bucket, b1, hbuf);

  // layer 2
  split_kernel<<<(N_NODES*F_HID/4+255)/256, 256, 0, stream>>>(hbuf, Hhi, Hlo, N_NODES*F_HID/4);
  gemm_mfma_kernel<F_HID><<<N_NODES/16, 256, 0, stream>>>(
      Hhi, Hlo, W2th, W2tl, al2, ar2, feat, el, er);
  edge_agg_kernel<0><<<N_NODES/4, 256, 0, stream>>>(
      (const bf16*)feat, el, er, cnt, bucket, b2, (float*)d_out);
}

// Round 9
// 197.848 us; speedup vs baseline: 1.1622x; 1.0602x over previous
//
#include <hip/hip_runtime.h>
#include <hip/hip_bf16.h>

#define N_NODES 20000
#define N_EDGES 320000
#define F_IN    128
#define F_HID   32
#define NHEAD   8
#define FDIM    256   // NHEAD * D for both layers
#define CAP     96    // max in-degree capacity; P(Poisson(16) > 96) ~ 1e-44

typedef __hip_bfloat16 bf16;
typedef __attribute__((ext_vector_type(8))) short short8;
typedef __attribute__((ext_vector_type(4))) float f32x4;

// bf16 round-to-nearest-even on raw bits
__device__ __forceinline__ unsigned short f2bf_rne(float f){
  unsigned u = __float_as_uint(f);
  unsigned r = u + 0x7FFFu + ((u >> 16) & 1u);
  return (unsigned short)(r >> 16);
}
__device__ __forceinline__ float bf2f(unsigned short s){
  return __uint_as_float((unsigned)s << 16);
}

// ---------------- bucket build ----------------
__global__ void fill_bucket_kernel(const int* __restrict__ src, const int* __restrict__ dst,
                                   int* __restrict__ cnt, int* __restrict__ bucket, int e){
  int i = blockIdx.x*256 + threadIdx.x;
  if (i < e){
    int d = dst[i];
    int p = atomicAdd(&cnt[d], 1);
    if (p < CAP) bucket[(size_t)d*CAP + p] = src[i];
  }
}

// ---------------- W1[K1][256],W2[K2][256] -> transposed hi/lo splits (one launch) ----------------
__global__ void splitT_both_kernel(const float* __restrict__ W1, const float* __restrict__ W2,
                                   unsigned short* __restrict__ h1, unsigned short* __restrict__ l1,
                                   unsigned short* __restrict__ h2, unsigned short* __restrict__ l2){
  int i = blockIdx.x*256 + threadIdx.x;
  const int n1 = FDIM*F_IN;
  if (i < n1){
    int n = i / F_IN, k = i - n*F_IN;
    float v = W1[(size_t)k*FDIM + n];
    unsigned short hs = f2bf_rne(v);
    h1[i] = hs;
    l1[i] = f2bf_rne(v - bf2f(hs));
  } else {
    int j = i - n1;
    int n = j / F_HID, k = j - n*F_HID;
    float v = W2[(size_t)k*FDIM + n];
    unsigned short hs = f2bf_rne(v);
    h2[j] = hs;
    l2[j] = f2bf_rne(v - bf2f(hs));
  }
}

// ---------------- MFMA GEMM: feat = X @ W (bf16x3 split) + el/er ----------------
// Block = 256 thr = 4 waves; block computes 16 rows x 256 cols.
// XSPLIT=1: X is fp32, hi/lo split done in-register at A-frag load (row is
// touched by exactly one block). XSPLIT=0: X is pre-split bf16 pair.
// bf16x3: D += Ah*Bh + Ah*Bl + Al*Bh (lo*lo dropped, ~2^-18 rel err).
// el/er from fp32 C fragments; C layout (m89): row=quad*4+r, col=lane&15.
template<int K, int XSPLIT>
__global__ __launch_bounds__(256) void gemm_mfma_kernel(
    const void* __restrict__ Xa, const void* __restrict__ Xb,
    const unsigned short* __restrict__ Wthi, const unsigned short* __restrict__ Wtlo,
    const float* __restrict__ al, const float* __restrict__ ar,
    unsigned short* __restrict__ feat, float* __restrict__ el, float* __restrict__ er)
{
  const int tid  = threadIdx.x;
  const int wv   = tid >> 6;
  const int lane = tid & 63;
  const int quad = lane >> 4;
  const int l16  = lane & 15;
  const int m0   = blockIdx.x * 16;
  constexpr int NC = K / 32;

  short8 Ah[NC], Al_[NC];
  if (XSPLIT){
    const float* xrow = (const float*)Xa + (size_t)(m0 + l16)*K;
    #pragma unroll
    for (int c = 0; c < NC; c++){
      float4 a0 = *(const float4*)(xrow + c*32 + quad*8);
      float4 a1 = *(const float4*)(xrow + c*32 + quad*8 + 4);
      const float vs[8] = {a0.x,a0.y,a0.z,a0.w,a1.x,a1.y,a1.z,a1.w};
      #pragma unroll
      for (int j = 0; j < 8; j++){
        unsigned short hs = f2bf_rne(vs[j]);
        Ah[c][j]  = (short)hs;
        Al_[c][j] = (short)f2bf_rne(vs[j] - bf2f(hs));
      }
    }
  } else {
    const size_t arow = (size_t)(m0 + l16) * K;
    #pragma unroll
    for (int c = 0; c < NC; c++){
      Ah[c]  = *(const short8*)((const unsigned short*)Xa + arow + c*32 + quad*8);
      Al_[c] = *(const short8*)((const unsigned short*)Xb + arow + c*32 + quad*8);
    }
  }

  float elp[8], erp[8];   // [r*2 + hloc], hloc = tile>>1
  #pragma unroll
  for (int j = 0; j < 8; j++){ elp[j] = 0.f; erp[j] = 0.f; }

  #pragma unroll
  for (int t = 0; t < 4; t++){
    const int nc = wv*64 + t*16;
    const size_t brow = (size_t)(nc + l16) * K;
    f32x4 acc = {0.f, 0.f, 0.f, 0.f};
    #pragma unroll
    for (int c = 0; c < NC; c++){
      short8 Bh = *(const short8*)(Wthi + brow + c*32 + quad*8);
      short8 Bl = *(const short8*)(Wtlo + brow + c*32 + quad*8);
      acc = __builtin_amdgcn_mfma_f32_16x16x32_bf16(Ah[c],  Bh, acc, 0, 0, 0);
      acc = __builtin_amdgcn_mfma_f32_16x16x32_bf16(Ah[c],  Bl, acc, 0, 0, 0);
      acc = __builtin_amdgcn_mfma_f32_16x16x32_bf16(Al_[c], Bh, acc, 0, 0, 0);
    }
    const float alv = al[nc + l16];
    const float arv = ar[nc + l16];
    const int hl = t >> 1;
    #pragma unroll
    for (int r = 0; r < 4; r++){
      float v = acc[r];
      feat[(size_t)(m0 + quad*4 + r)*FDIM + nc + l16] = f2bf_rne(v);
      elp[r*2 + hl] = fmaf(v, alv, elp[r*2 + hl]);
      erp[r*2 + hl] = fmaf(v, arv, erp[r*2 + hl]);
    }
  }

  #pragma unroll
  for (int off = 1; off <= 8; off <<= 1){
    #pragma unroll
    for (int j = 0; j < 8; j++){
      elp[j] += __shfl_xor(elp[j], off);
      erp[j] += __shfl_xor(erp[j], off);
    }
  }
  __shared__ float el_lds[16][8], er_lds[16][8];
  if (l16 == 0){
    #pragma unroll
    for (int r = 0; r < 4; r++){
      #pragma unroll
      for (int hl = 0; hl < 2; hl++){
        el_lds[quad*4 + r][wv*2 + hl] = elp[r*2 + hl];
        er_lds[quad*4 + r][wv*2 + hl] = erp[r*2 + hl];
      }
    }
  }
  __syncthreads();
  if (tid < 128){
    int row = tid >> 3, h = tid & 7;
    el[(size_t)(m0 + row)*NHEAD + h] = el_lds[row][h];
    er[(size_t)(m0 + row)*NHEAD + h] = er_lds[row][h];
  }
}

// ---------------- per-dst-node edge softmax + aggregate ----------------
// WAVE-PER-NODE: 4 waves/block, zero __syncthreads.
// SPLIT_OUT=1: relu(mean(heads)) written as bf16 hi/lo pair (feeds gemm2's
// pre-split A path — identical numerics to fp32 store + separate split).
// SPLIT_OUT=0: mean(heads) written fp32 to outp.
template<int SPLIT_OUT>
__global__ __launch_bounds__(256) void edge_agg_kernel(
    const bf16* __restrict__ feat, const float* __restrict__ el,
    const float* __restrict__ er, const int* __restrict__ cnt,
    const int* __restrict__ bucket, const float* __restrict__ bias,
    float* __restrict__ outp,
    unsigned short* __restrict__ ohi, unsigned short* __restrict__ olo)
{
  const int tid  = threadIdx.x;
  const int wv   = tid >> 6;
  const int lane = tid & 63;
  const int n    = blockIdx.x*4 + wv;

  __shared__ float t_all[4][CAP*9];   // stride 9: conflict-free
  __shared__ int   s_all[4][CAP];
  __shared__ float sum_all[4][NHEAD];
  __shared__ float v_all[4][256];
  float* t_w = t_all[wv];
  int*   s_w = s_all[wv];

  int C = cnt[n];
  if (C > CAP) C = CAP;

  const float4* er4 = (const float4*)(er + (size_t)n*NHEAD);
  float4 era = er4[0], erb = er4[1];
  const float erv[8] = {era.x, era.y, era.z, era.w, erb.x, erb.y, erb.z, erb.w};

  // ---- Phase A: logits ----
  for (int e = lane; e < C; e += 64){
    const int sidx = bucket[(size_t)n*CAP + e];
    s_w[e] = sidx;
    const float4* e4 = (const float4*)(el + (size_t)sidx*NHEAD);
    float4 a = e4[0], bq = e4[1];
    float ev[8] = {a.x, a.y, a.z, a.w, bq.x, bq.y, bq.z, bq.w};
    #pragma unroll
    for (int hh = 0; hh < 8; hh++){
      float v = ev[hh] + erv[hh];
      t_w[e*9 + hh] = (v > 0.f) ? v : 0.2f*v;   // leaky_relu(0.2)
    }
  }
  // per-head max + exp + denominator: 8 lanes per head
  {
    const int h = lane >> 3, d = lane & 7;
    float lm = -INFINITY;
    for (int e = d; e < C; e += 8) lm = fmaxf(lm, t_w[e*9 + h]);
    #pragma unroll
    for (int off = 4; off >= 1; off >>= 1) lm = fmaxf(lm, __shfl_xor(lm, off));
    float ls = 0.f;
    for (int e = d; e < C; e += 8){
      float ex = __expf(t_w[e*9 + h] - lm);
      t_w[e*9 + h] = ex;
      ls += ex;
    }
    #pragma unroll
    for (int off = 4; off >= 1; off >>= 1) ls += __shfl_xor(ls, off);
    if (d == 0) sum_all[wv][h] = ls;
  }

  // ---- Phase B: weighted aggregation, half-wave per edge, dwordx4 bf16 ----
  const int sub = lane >> 5;
  const int l   = lane & 31;
  const int hB  = l >> 2;
  float acc[8] = {0,0,0,0,0,0,0,0};
  for (int e = sub; e < C; e += 2){
    const int sidx = s_w[e];
    const float4 fv = *(const float4*)(feat + (size_t)sidx*FDIM + (l << 3));
    const float w = t_w[e*9 + hB];
    const unsigned* u = (const unsigned*)&fv;
    #pragma unroll
    for (int j = 0; j < 4; j++){
      float flo = __uint_as_float(u[j] << 16);
      float fhi = __uint_as_float(u[j] & 0xFFFF0000u);
      acc[2*j]   = fmaf(w, flo, acc[2*j]);
      acc[2*j+1] = fmaf(w, fhi, acc[2*j+1]);
    }
  }
  #pragma unroll
  for (int j = 0; j < 8; j++) acc[j] += __shfl_xor(acc[j], 32);

  // ---- epilogue (wave-local): divide, bias, (relu), head-mean ----
  if (lane < 32){
    const float s = sum_all[wv][l >> 2];
    const float4* b4 = (const float4*)(bias + (l << 3));
    float4 ba = b4[0], bb = b4[1];
    float bv[8] = {ba.x, ba.y, ba.z, ba.w, bb.x, bb.y, bb.z, bb.w};
    float v[8];
    #pragma unroll
    for (int j = 0; j < 8; j++){
      float val = (C > 0) ? (acc[j] / s) : 0.f;
      val += bv[j];
      if (SPLIT_OUT) val = fmaxf(val, 0.f);   // relu only on layer-1 path
      v[j] = val;
    }
    float4* v4 = (float4*)&v_all[wv][l << 3];
    v4[0] = make_float4(v[0], v[1], v[2], v[3]);
    v4[1] = make_float4(v[4], v[5], v[6], v[7]);
  }
  if (lane < 32){
    float sum = 0.f;
    #pragma unroll
    for (int hh = 0; hh < 8; hh++) sum += v_all[wv][hh*32 + lane];
    sum *= 0.125f;   // mean over heads
    if (SPLIT_OUT){
      unsigned short hs = f2bf_rne(sum);
      ohi[(size_t)n*32 + lane] = hs;
      olo[(size_t)n*32 + lane] = f2bf_rne(sum - bf2f(hs));
    } else {
      outp[(size_t)n*32 + lane] = sum;
    }
  }
}

extern "C" void kernel_launch(void* const* d_in, const int* in_sizes, int n_in,
                              void* d_out, int out_size, void* d_ws, size_t ws_size,
                              hipStream_t stream)
{
  const float* x   = (const float*)d_in[0];
  const int*   src = (const int*)  d_in[1];
  const int*   dst = (const int*)  d_in[2];
  const float* W1  = (const float*)d_in[3];
  const float* al1 = (const float*)d_in[4];
  const float* ar1 = (const float*)d_in[5];
  const float* b1  = (const float*)d_in[6];
  const float* W2  = (const float*)d_in[7];
  const float* al2 = (const float*)d_in[8];
  const float* ar2 = (const float*)d_in[9];
  const float* b2  = (const float*)d_in[10];
  (void)in_sizes; (void)n_in; (void)out_size; (void)ws_size;

  size_t o = 0;
  char* base = (char*)d_ws;
  auto take = [&](size_t bytes) -> char* {
    char* p = base + o;
    o += (bytes + 255) & ~(size_t)255;
    return p;
  };
  unsigned short* feat  = (unsigned short*)take((size_t)N_NODES*FDIM*2);
  float* el     = (float*)take((size_t)N_NODES*NHEAD*4);
  float* er     = (float*)take((size_t)N_NODES*NHEAD*4);
  int*   cnt    = (int*)  take((size_t)N_NODES*4);
  int*   bucket = (int*)  take((size_t)N_NODES*CAP*4);
  unsigned short* Hhi  = (unsigned short*)take((size_t)N_NODES*F_HID*2);
  unsigned short* Hlo  = (unsigned short*)take((size_t)N_NODES*F_HID*2);
  unsigned short* W1th = (unsigned short*)take((size_t)FDIM*F_IN*2);
  unsigned short* W1tl = (unsigned short*)take((size_t)FDIM*F_IN*2);
  unsigned short* W2th = (unsigned short*)take((size_t)FDIM*F_HID*2);
  unsigned short* W2tl = (unsigned short*)take((size_t)FDIM*F_HID*2);

  // prep: counter clear (memset node), bucket fill, fused W splits
  hipMemsetAsync(cnt, 0, (size_t)N_NODES*4, stream);
  fill_bucket_kernel<<<(N_EDGES+255)/256, 256, 0, stream>>>(src, dst, cnt, bucket, N_EDGES);
  splitT_both_kernel<<<(FDIM*(F_IN+F_HID))/256, 256, 0, stream>>>(
      W1, W2, W1th, W1tl, W2th, W2tl);

  // layer 1 (x split in-register inside the gemm)
  gemm_mfma_kernel<F_IN, 1><<<N_NODES/16, 256, 0, stream>>>(
      x, nullptr, W1th, W1tl, al1, ar1, feat, el, er);
  edge_agg_kernel<1><<<N_NODES/4, 256, 0, stream>>>(
      (const bf16*)feat, el, er, cnt, bucket, b1, nullptr, Hhi, Hlo);

  // layer 2 (pre-split A from edge_agg's epilogue)
  gemm_mfma_kernel<F_HID, 0><<<N_NODES/16, 256, 0, stream>>>(
      Hhi, Hlo, W2th, W2tl, al2, ar2, feat, el, er);
  edge_agg_kernel<0><<<N_NODES/4, 256, 0, stream>>>(
      (const bf16*)feat, el, er, cnt, bucket, b2, (float*)d_out, nullptr, nullptr);
}

// Round 10
// 197.456 us; speedup vs baseline: 1.1645x; 1.0020x over previous
//
#include <hip/hip_runtime.h>
#include <hip/hip_bf16.h>

#define N_NODES 20000
#define N_EDGES 320000
#define F_IN    128
#define F_HID   32
#define NHEAD   8
#define FDIM    256   // NHEAD * D for both layers
#define CAP     96    // max in-degree capacity; P(Poisson(16) > 96) ~ 1e-44

typedef __hip_bfloat16 bf16;
typedef __attribute__((ext_vector_type(8))) short short8;
typedef __attribute__((ext_vector_type(4))) float f32x4;

// bf16 round-to-nearest-even on raw bits
__device__ __forceinline__ unsigned short f2bf_rne(float f){
  unsigned u = __float_as_uint(f);
  unsigned r = u + 0x7FFFu + ((u >> 16) & 1u);
  return (unsigned short)(r >> 16);
}
__device__ __forceinline__ float bf2f(unsigned short s){
  return __uint_as_float((unsigned)s << 16);
}

// ---------------- fused prep: bucket fill + W transpose/splits ----------------
// blocks [0, FILLB): scatter edges into per-dst buckets
// blocks [FILLB, FILLB+SPLITB): W1/W2 -> transposed bf16 hi/lo splits
#define FILLB  ((N_EDGES + 255) / 256)
#define SPLITB ((FDIM * (F_IN + F_HID)) / 256)
__global__ void prep_kernel(const int* __restrict__ src, const int* __restrict__ dst,
                            int* __restrict__ cnt, int* __restrict__ bucket,
                            const float* __restrict__ W1, const float* __restrict__ W2,
                            unsigned short* __restrict__ h1, unsigned short* __restrict__ l1,
                            unsigned short* __restrict__ h2, unsigned short* __restrict__ l2){
  const int b = blockIdx.x;
  if (b < FILLB){
    int i = b*256 + threadIdx.x;
    if (i < N_EDGES){
      int d = dst[i];
      int p = atomicAdd(&cnt[d], 1);
      if (p < CAP) bucket[(size_t)d*CAP + p] = src[i];
    }
  } else {
    int i = (b - FILLB)*256 + threadIdx.x;
    const int n1 = FDIM*F_IN;
    if (i < n1){
      int n = i / F_IN, k = i - n*F_IN;
      float v = W1[(size_t)k*FDIM + n];
      unsigned short hs = f2bf_rne(v);
      h1[i] = hs;
      l1[i] = f2bf_rne(v - bf2f(hs));
    } else {
      int j = i - n1;
      int n = j / F_HID, k = j - n*F_HID;
      float v = W2[(size_t)k*FDIM + n];
      unsigned short hs = f2bf_rne(v);
      h2[j] = hs;
      l2[j] = f2bf_rne(v - bf2f(hs));
    }
  }
}

// ---------------- MFMA GEMM: feat = X @ W (bf16x3 split) + el/er ----------------
// Block = 256 thr = 4 waves; block computes 16 rows x 256 cols.
// XSPLIT=1: X fp32, hi/lo split in-register at A-frag load. XSPLIT=0: pre-split.
// bf16x3: D += Ah*Bh + Ah*Bl + Al*Bh (lo*lo dropped, ~2^-18 rel err).
// C layout (m89): row=quad*4+r, col=lane&15.
template<int K, int XSPLIT>
__global__ __launch_bounds__(256) void gemm_mfma_kernel(
    const void* __restrict__ Xa, const void* __restrict__ Xb,
    const unsigned short* __restrict__ Wthi, const unsigned short* __restrict__ Wtlo,
    const float* __restrict__ al, const float* __restrict__ ar,
    unsigned short* __restrict__ feat, float* __restrict__ el, float* __restrict__ er)
{
  const int tid  = threadIdx.x;
  const int wv   = tid >> 6;
  const int lane = tid & 63;
  const int quad = lane >> 4;
  const int l16  = lane & 15;
  const int m0   = blockIdx.x * 16;
  constexpr int NC = K / 32;

  short8 Ah[NC], Al_[NC];
  if (XSPLIT){
    const float* xrow = (const float*)Xa + (size_t)(m0 + l16)*K;
    #pragma unroll
    for (int c = 0; c < NC; c++){
      float4 a0 = *(const float4*)(xrow + c*32 + quad*8);
      float4 a1 = *(const float4*)(xrow + c*32 + quad*8 + 4);
      const float vs[8] = {a0.x,a0.y,a0.z,a0.w,a1.x,a1.y,a1.z,a1.w};
      #pragma unroll
      for (int j = 0; j < 8; j++){
        unsigned short hs = f2bf_rne(vs[j]);
        Ah[c][j]  = (short)hs;
        Al_[c][j] = (short)f2bf_rne(vs[j] - bf2f(hs));
      }
    }
  } else {
    const size_t arow = (size_t)(m0 + l16) * K;
    #pragma unroll
    for (int c = 0; c < NC; c++){
      Ah[c]  = *(const short8*)((const unsigned short*)Xa + arow + c*32 + quad*8);
      Al_[c] = *(const short8*)((const unsigned short*)Xb + arow + c*32 + quad*8);
    }
  }

  float elp[8], erp[8];   // [r*2 + hloc], hloc = tile>>1
  #pragma unroll
  for (int j = 0; j < 8; j++){ elp[j] = 0.f; erp[j] = 0.f; }

  #pragma unroll
  for (int t = 0; t < 4; t++){
    const int nc = wv*64 + t*16;
    const size_t brow = (size_t)(nc + l16) * K;
    f32x4 acc = {0.f, 0.f, 0.f, 0.f};
    #pragma unroll
    for (int c = 0; c < NC; c++){
      short8 Bh = *(const short8*)(Wthi + brow + c*32 + quad*8);
      short8 Bl = *(const short8*)(Wtlo + brow + c*32 + quad*8);
      acc = __builtin_amdgcn_mfma_f32_16x16x32_bf16(Ah[c],  Bh, acc, 0, 0, 0);
      acc = __builtin_amdgcn_mfma_f32_16x16x32_bf16(Ah[c],  Bl, acc, 0, 0, 0);
      acc = __builtin_amdgcn_mfma_f32_16x16x32_bf16(Al_[c], Bh, acc, 0, 0, 0);
    }
    const float alv = al[nc + l16];
    const float arv = ar[nc + l16];
    const int hl = t >> 1;
    #pragma unroll
    for (int r = 0; r < 4; r++){
      float v = acc[r];
      feat[(size_t)(m0 + quad*4 + r)*FDIM + nc + l16] = f2bf_rne(v);
      elp[r*2 + hl] = fmaf(v, alv, elp[r*2 + hl]);
      erp[r*2 + hl] = fmaf(v, arv, erp[r*2 + hl]);
    }
  }

  #pragma unroll
  for (int off = 1; off <= 8; off <<= 1){
    #pragma unroll
    for (int j = 0; j < 8; j++){
      elp[j] += __shfl_xor(elp[j], off);
      erp[j] += __shfl_xor(erp[j], off);
    }
  }
  __shared__ float el_lds[16][8], er_lds[16][8];
  if (l16 == 0){
    #pragma unroll
    for (int r = 0; r < 4; r++){
      #pragma unroll
      for (int hl = 0; hl < 2; hl++){
        el_lds[quad*4 + r][wv*2 + hl] = elp[r*2 + hl];
        er_lds[quad*4 + r][wv*2 + hl] = erp[r*2 + hl];
      }
    }
  }
  __syncthreads();
  if (tid < 128){
    int row = tid >> 3, h = tid & 7;
    el[(size_t)(m0 + row)*NHEAD + h] = el_lds[row][h];
    er[(size_t)(m0 + row)*NHEAD + h] = er_lds[row][h];
  }
}

// ---------------- per-dst-node edge softmax + aggregate ----------------
// WAVE-PER-NODE: 4 waves/block, zero __syncthreads. Phase A: 2 lanes per edge
// (each loads one float4 of el -> 4 heads). Phase B: half-wave per edge,
// dwordx4 bf16 gathers, SOFTWARE-PIPELINED (next gather issued before current
// consume -> 2 loads in flight; the per-iter vmcnt(0) chain was the round-9
// latency bottleneck).
template<int SPLIT_OUT>
__global__ __launch_bounds__(256) void edge_agg_kernel(
    const bf16* __restrict__ feat, const float* __restrict__ el,
    const float* __restrict__ er, const int* __restrict__ cnt,
    const int* __restrict__ bucket, const float* __restrict__ bias,
    float* __restrict__ outp,
    unsigned short* __restrict__ ohi, unsigned short* __restrict__ olo)
{
  const int tid  = threadIdx.x;
  const int wv   = tid >> 6;
  const int lane = tid & 63;
  const int n    = blockIdx.x*4 + wv;

  __shared__ float t_all[4][CAP*9];   // stride 9: conflict-free
  __shared__ int   s_all[4][CAP];
  __shared__ float sum_all[4][NHEAD];
  __shared__ float v_all[4][256];
  float* t_w = t_all[wv];
  int*   s_w = s_all[wv];

  int C = cnt[n];
  if (C > CAP) C = CAP;

  const float4* er4 = (const float4*)(er + (size_t)n*NHEAD);
  float4 era = er4[0], erb = er4[1];
  const float erv[8] = {era.x, era.y, era.z, era.w, erb.x, erb.y, erb.z, erb.w};

  // ---- Phase A: logits, 2 lanes per edge (j = which float4 of el) ----
  for (int idx = lane; idx < C*2; idx += 64){
    const int e = idx >> 1, j = idx & 1;
    const int sidx = bucket[(size_t)n*CAP + e];
    if (j == 0) s_w[e] = sidx;
    float4 a = ((const float4*)(el + (size_t)sidx*NHEAD))[j];
    const float ev[4] = {a.x, a.y, a.z, a.w};
    #pragma unroll
    for (int hh = 0; hh < 4; hh++){
      float v = ev[hh] + erv[j*4 + hh];
      t_w[e*9 + j*4 + hh] = (v > 0.f) ? v : 0.2f*v;   // leaky_relu(0.2)
    }
  }
  // per-head max + exp + denominator: 8 lanes per head
  {
    const int h = lane >> 3, d = lane & 7;
    float lm = -INFINITY;
    for (int e = d; e < C; e += 8) lm = fmaxf(lm, t_w[e*9 + h]);
    #pragma unroll
    for (int off = 4; off >= 1; off >>= 1) lm = fmaxf(lm, __shfl_xor(lm, off));
    float ls = 0.f;
    for (int e = d; e < C; e += 8){
      float ex = __expf(t_w[e*9 + h] - lm);
      t_w[e*9 + h] = ex;
      ls += ex;
    }
    #pragma unroll
    for (int off = 4; off >= 1; off >>= 1) ls += __shfl_xor(ls, off);
    if (d == 0) sum_all[wv][h] = ls;
  }

  // ---- Phase B: pipelined weighted aggregation ----
  const int sub = lane >> 5;
  const int l   = lane & 31;
  const int hB  = l >> 2;
  const int coff = l << 3;
  float acc[8] = {0,0,0,0,0,0,0,0};
  int e = sub;
  float4 fv;
  if (e < C) fv = *(const float4*)(feat + (size_t)s_w[e]*FDIM + coff);
  while (e < C){
    const int en = e + 2;
    float4 fnext;
    if (en < C) fnext = *(const float4*)(feat + (size_t)s_w[en]*FDIM + coff);
    const float w = t_w[e*9 + hB];
    const unsigned* u = (const unsigned*)&fv;
    #pragma unroll
    for (int j = 0; j < 4; j++){
      float flo = __uint_as_float(u[j] << 16);
      float fhi = __uint_as_float(u[j] & 0xFFFF0000u);
      acc[2*j]   = fmaf(w, flo, acc[2*j]);
      acc[2*j+1] = fmaf(w, fhi, acc[2*j+1]);
    }
    fv = fnext;
    e = en;
  }
  #pragma unroll
  for (int j = 0; j < 8; j++) acc[j] += __shfl_xor(acc[j], 32);

  // ---- epilogue (wave-local): divide, bias, (relu), head-mean ----
  if (lane < 32){
    const float s = sum_all[wv][l >> 2];
    const float4* b4 = (const float4*)(bias + coff);
    float4 ba = b4[0], bb = b4[1];
    float bv[8] = {ba.x, ba.y, ba.z, ba.w, bb.x, bb.y, bb.z, bb.w};
    float v[8];
    #pragma unroll
    for (int j = 0; j < 8; j++){
      float val = (C > 0) ? (acc[j] / s) : 0.f;
      val += bv[j];
      if (SPLIT_OUT) val = fmaxf(val, 0.f);   // relu only on layer-1 path
      v[j] = val;
    }
    float4* v4 = (float4*)&v_all[wv][coff];
    v4[0] = make_float4(v[0], v[1], v[2], v[3]);
    v4[1] = make_float4(v[4], v[5], v[6], v[7]);
  }
  if (lane < 32){
    float sum = 0.f;
    #pragma unroll
    for (int hh = 0; hh < 8; hh++) sum += v_all[wv][hh*32 + lane];
    sum *= 0.125f;   // mean over heads
    if (SPLIT_OUT){
      unsigned short hs = f2bf_rne(sum);
      ohi[(size_t)n*32 + lane] = hs;
      olo[(size_t)n*32 + lane] = f2bf_rne(sum - bf2f(hs));
    } else {
      outp[(size_t)n*32 + lane] = sum;
    }
  }
}

extern "C" void kernel_launch(void* const* d_in, const int* in_sizes, int n_in,
                              void* d_out, int out_size, void* d_ws, size_t ws_size,
                              hipStream_t stream)
{
  const float* x   = (const float*)d_in[0];
  const int*   src = (const int*)  d_in[1];
  const int*   dst = (const int*)  d_in[2];
  const float* W1  = (const float*)d_in[3];
  const float* al1 = (const float*)d_in[4];
  const float* ar1 = (const float*)d_in[5];
  const float* b1  = (const float*)d_in[6];
  const float* W2  = (const float*)d_in[7];
  const float* al2 = (const float*)d_in[8];
  const float* ar2 = (const float*)d_in[9];
  const float* b2  = (const float*)d_in[10];
  (void)in_sizes; (void)n_in; (void)out_size; (void)ws_size;

  size_t o = 0;
  char* base = (char*)d_ws;
  auto take = [&](size_t bytes) -> char* {
    char* p = base + o;
    o += (bytes + 255) & ~(size_t)255;
    return p;
  };
  unsigned short* feat  = (unsigned short*)take((size_t)N_NODES*FDIM*2);
  float* el     = (float*)take((size_t)N_NODES*NHEAD*4);
  float* er     = (float*)take((size_t)N_NODES*NHEAD*4);
  int*   cnt    = (int*)  take((size_t)N_NODES*4);
  int*   bucket = (int*)  take((size_t)N_NODES*CAP*4);
  unsigned short* Hhi  = (unsigned short*)take((size_t)N_NODES*F_HID*2);
  unsigned short* Hlo  = (unsigned short*)take((size_t)N_NODES*F_HID*2);
  unsigned short* W1th = (unsigned short*)take((size_t)FDIM*F_IN*2);
  unsigned short* W1tl = (unsigned short*)take((size_t)FDIM*F_IN*2);
  unsigned short* W2th = (unsigned short*)take((size_t)FDIM*F_HID*2);
  unsigned short* W2tl = (unsigned short*)take((size_t)FDIM*F_HID*2);

  // prep: counter clear (memset), fused bucket-fill + W splits
  hipMemsetAsync(cnt, 0, (size_t)N_NODES*4, stream);
  prep_kernel<<<FILLB + SPLITB, 256, 0, stream>>>(
      src, dst, cnt, bucket, W1, W2, W1th, W1tl, W2th, W2tl);

  // layer 1 (x split in-register inside the gemm)
  gemm_mfma_kernel<F_IN, 1><<<N_NODES/16, 256, 0, stream>>>(
      x, nullptr, W1th, W1tl, al1, ar1, feat, el, er);
  edge_agg_kernel<1><<<N_NODES/4, 256, 0, stream>>>(
      (const bf16*)feat, el, er, cnt, bucket, b1, nullptr, Hhi, Hlo);

  // layer 2 (pre-split A from edge_agg's epilogue)
  gemm_mfma_kernel<F_HID, 0><<<N_NODES/16, 256, 0, stream>>>(
      Hhi, Hlo, W2th, W2tl, al2, ar2, feat, el, er);
  edge_agg_kernel<0><<<N_NODES/4, 256, 0, stream>>>(
      (const bf16*)feat, el, er, cnt, bucket, b2, (float*)d_out, nullptr, nullptr);
}